// Round 8
// baseline (180.132 us; speedup 1.0000x reference)
//
#include <hip/hip_runtime.h>

// out[b,h,w,d] = sum_c x[b,h,w,c] * w[c,d]   with C=D=3, fp32.
//
// R8: pixel-granular lanes. Lane handles one whole pixel = 12B (dwordx3),
// lane-stride 12B -> each wave-instr covers a contiguous 768B (~13 lines),
// near-probe footprint. Body = load -> 9 FMA -> store: no shuffles, no
// phase selects, no divergence, no modulo => load-issue duty ~95%
// (R7's shuffle/lgkm chain held duty ~60% -> 3.3 TB/s).
// Hand-unrolled x4 with all 4 loads hoisted: 48B/lane outstanding
// (3KB/wave, ~3x the 36us-probe's depth). Plain stores (not nt): L2
// merges 12B-stride writes (R5 showed nt partial-line stores amplify
// WRITE 1.7x; R1/R3 plain stores were clean 98MB).

struct Px { float c0, c1, c2; };   // 12 bytes, align 4 -> global_load_dwordx3

#define BLOCK 256
#define GRID 2048

__global__ __launch_bounds__(BLOCK) void mct_kernel(
    const float* __restrict__ x,
    const float* __restrict__ w,
    float* __restrict__ out,
    long long n_pixels)
{
    const Px* __restrict__ src = reinterpret_cast<const Px*>(x);
    Px* __restrict__ dst = reinterpret_cast<Px*>(out);

    const float w00 = w[0], w01 = w[1], w02 = w[2];
    const float w10 = w[3], w11 = w[4], w12 = w[5];
    const float w20 = w[6], w21 = w[7], w22 = w[8];

    const long long S = (long long)GRID * BLOCK;           // 524,288
    long long p = (long long)blockIdx.x * BLOCK + threadIdx.x;

    // Macro loop: 4 pixels per iteration, loads hoisted for MLP.
    for (; p + 3 * S < n_pixels; p += 4 * S) {
        Px a = src[p];
        Px b = src[p + S];
        Px c = src[p + 2 * S];
        Px d = src[p + 3 * S];

        Px oa, ob, oc, od;
        oa.c0 = a.c0 * w00 + a.c1 * w10 + a.c2 * w20;
        oa.c1 = a.c0 * w01 + a.c1 * w11 + a.c2 * w21;
        oa.c2 = a.c0 * w02 + a.c1 * w12 + a.c2 * w22;

        ob.c0 = b.c0 * w00 + b.c1 * w10 + b.c2 * w20;
        ob.c1 = b.c0 * w01 + b.c1 * w11 + b.c2 * w21;
        ob.c2 = b.c0 * w02 + b.c1 * w12 + b.c2 * w22;

        oc.c0 = c.c0 * w00 + c.c1 * w10 + c.c2 * w20;
        oc.c1 = c.c0 * w01 + c.c1 * w11 + c.c2 * w21;
        oc.c2 = c.c0 * w02 + c.c1 * w12 + c.c2 * w22;

        od.c0 = d.c0 * w00 + d.c1 * w10 + d.c2 * w20;
        od.c1 = d.c0 * w01 + d.c1 * w11 + d.c2 * w21;
        od.c2 = d.c0 * w02 + d.c1 * w12 + d.c2 * w22;

        dst[p]         = oa;
        dst[p + S]     = ob;
        dst[p + 2 * S] = oc;
        dst[p + 3 * S] = od;
    }

    // Remainder (empty for bench shape: 8,388,608 = 16 * 524,288).
    for (; p < n_pixels; p += S) {
        Px a = src[p];
        Px o;
        o.c0 = a.c0 * w00 + a.c1 * w10 + a.c2 * w20;
        o.c1 = a.c0 * w01 + a.c1 * w11 + a.c2 * w21;
        o.c2 = a.c0 * w02 + a.c1 * w12 + a.c2 * w22;
        dst[p] = o;
    }
}

extern "C" void kernel_launch(void* const* d_in, const int* in_sizes, int n_in,
                              void* d_out, int out_size, void* d_ws, size_t ws_size,
                              hipStream_t stream) {
    const float* x = (const float*)d_in[0];
    const float* w = (const float*)d_in[1];
    float* out = (float*)d_out;

    const long long n_total  = (long long)in_sizes[0];   // 32*512*512*3
    const long long n_pixels = n_total / 3;

    mct_kernel<<<GRID, BLOCK, 0, stream>>>(x, w, out, n_pixels);
}